// Round 6
// baseline (867.500 us; speedup 1.0000x reference)
//
#include <hip/hip_runtime.h>

#define NN 10000
#define BB 32
#define EE 40000
#define HH 4
#define DD 10
#define TT 10
#define NEG 0.2f

#define NB   (NN*BB)          // 320000
#define NBH_T (NB*HH)         // 1280000 threads for gat kernels
#define NBT  (NN*BB*TT)       // 3200000

// ---------------- extract mu/sigma + regression heads ----------------
__global__ void extract_kernel(const float* __restrict__ x,
                               const float* __restrict__ wmu, const float* __restrict__ bmu,
                               const float* __restrict__ wsg, const float* __restrict__ bsg,
                               float* __restrict__ mu, float* __restrict__ sg,
                               float* __restrict__ regmu, float* __restrict__ regsg) {
    int i = blockIdx.x * blockDim.x + threadIdx.x;   // over N*B
    if (i >= NB) return;
    int n = i / BB, b = i % BB;
    float smu = 0.f, ssg = 0.f;
    float muv[TT], sgv[TT];
#pragma unroll
    for (int t = 0; t < TT; t++) {
        size_t xi = (((size_t)t * NN + n) * BB + b) * 3;
        float m = x[xi], s = x[xi + 1];
        muv[t] = m; sgv[t] = s;
        smu += m * wmu[t];
        ssg += s * wsg[t];
    }
#pragma unroll
    for (int t = 0; t < TT; t++) {
        mu[(size_t)i * TT + t] = muv[t];
        sg[(size_t)i * TT + t] = sgv[t];
    }
    regmu[i] = smu + bmu[0];
    regsg[i] = ssg + bsg[0];
}

// ---------------- CSR build ----------------
__global__ void deg_kernel(const int* __restrict__ dst, int* __restrict__ deg) {
    int e = blockIdx.x * blockDim.x + threadIdx.x;
    if (e < EE) atomicAdd(&deg[dst[e]], 1);
}

__global__ void scan_kernel(const int* __restrict__ deg, int* __restrict__ off) {
    __shared__ int sm[1024];
    __shared__ int carry_s;
    if (threadIdx.x == 0) { carry_s = 0; off[0] = 0; }
    __syncthreads();
    for (int base = 0; base < NN; base += 1024) {
        int i = base + (int)threadIdx.x;
        int v = (i < NN) ? deg[i] : 0;
        sm[threadIdx.x] = v;
        __syncthreads();
        for (int s = 1; s < 1024; s <<= 1) {
            int t = (threadIdx.x >= (unsigned)s) ? sm[threadIdx.x - s] : 0;
            __syncthreads();
            sm[threadIdx.x] += t;
            __syncthreads();
        }
        if (i < NN) off[i + 1] = carry_s + sm[threadIdx.x];
        __syncthreads();
        if (threadIdx.x == 0) carry_s += sm[1023];
        __syncthreads();
    }
}

__global__ void fill_kernel(const int* __restrict__ src, const int* __restrict__ dst,
                            const int* __restrict__ off, int* __restrict__ cursor,
                            int* __restrict__ csr_src) {
    int e = blockIdx.x * blockDim.x + threadIdx.x;
    if (e < EE) {
        int d = dst[e];
        int p = atomicAdd(&cursor[d], 1);
        csr_src[off[d] + p] = src[e];
    }
}

// ---------------- precompute vl/vr for all 8 GATs ----------------
// vbuf layout: 8 slots of [vl(H*T=40) | vr(40)];
// slot g: which = g&3 in {mu_p, sg_p, mu_r, sg_r}, layer = g>>2
__global__ void vpre_kernel(const float* __restrict__ fc0, const float* __restrict__ al0, const float* __restrict__ ar0,
                            const float* __restrict__ fc1, const float* __restrict__ al1, const float* __restrict__ ar1,
                            const float* __restrict__ fc2, const float* __restrict__ al2, const float* __restrict__ ar2,
                            const float* __restrict__ fc3, const float* __restrict__ al3, const float* __restrict__ ar3,
                            float* __restrict__ vbuf) {
    int j = threadIdx.x;                 // 0..319
    if (j >= 320) return;
    int g = j / 40, r = j % 40;
    int h = r / 10, t = r % 10;
    int which = g & 3, layer = g >> 2;
    const float* fc; const float* al; const float* ar;
    if (which == 0)      { fc = fc0; al = al0; ar = ar0; }
    else if (which == 1) { fc = fc1; al = al1; ar = ar1; }
    else if (which == 2) { fc = fc2; al = al2; ar = ar2; }
    else                 { fc = fc3; al = al3; ar = ar3; }
    fc += layer * (HH * DD * TT);
    al += layer * (HH * DD);
    ar += layer * (HH * DD);
    float vl = 0.f, vr = 0.f;
#pragma unroll
    for (int d = 0; d < DD; d++) {
        float w = fc[(h * DD + d) * TT + t];
        vl += al[h * DD + d] * w;
        vr += ar[h * DD + d] * w;
    }
    vbuf[g * 80 + r] = vl;
    vbuf[g * 80 + 40 + r] = vr;
}

// ---------------- single-GAT, thread per (node, batch, head) ----------------
// History of the register-allocator fight:
//   r2 dual-GAT per-(n,b): live ~170, allocator chose 64 -> 800 MB HBM spill.
//   r3 +bounds(256,2): chose 128, still spilled, worse.
//   r4/r5 dual-GAT per-(n,b,h): live ~85, allocator chose 64 both with and
//      without bounds(256,4) -> scratch spill (L2-absorbed), 268 us/dispatch,
//      latency-bound at 31% occupancy.
// Fix: SINGLE GAT per dispatch. Live set: acc[10] + fa[10] + fb[10] (2-edge
// software pipeline) + ~10 scalars ~= 40-45 VGPRs -- fits the 64 tier with
// margin. vl/vr live in LDS (quad-broadcast reads are conflict-free).
// Wave layout: i = (nb<<2)|h -> 16 consecutive nb x 4 heads, one node per
// wave, so the edge loop is wave-uniform and the 16 nb-rows (40 B each,
// consecutive b) coalesce into a contiguous 640 B block per edge.
template <bool STATS>
__global__ void __launch_bounds__(256)
gat1_kernel(const float* __restrict__ f, const float* __restrict__ W,
            const float* __restrict__ v, const int* __restrict__ off,
            const int* __restrict__ csr_src, float* __restrict__ g,
            float* __restrict__ stats) {
    __shared__ float sW[HH * DD * TT];      // 400
    __shared__ float sv[2 * HH * TT];       // 80: [vl(40) | vr(40)]
    for (int k = threadIdx.x; k < HH * DD * TT; k += blockDim.x) sW[k] = W[k];
    if (threadIdx.x < 2 * HH * TT) sv[threadIdx.x] = v[threadIdx.x];
    __syncthreads();

    int i = blockIdx.x * blockDim.x + threadIdx.x;   // over NB*HH
    float lsum = 0.f, lsq = 0.f;
    if (i < NBH_T) {
        int h  = i & 3;
        int nb = i >> 2;          // n*32 + b
        int b  = nb & 31;
        int n  = nb >> 5;
        int s0 = off[n], s1 = off[n + 1];

        // er from self features
        float er = 0.f;
        {
            const float* p = f + (size_t)nb * TT;
#pragma unroll
            for (int t = 0; t < TT; t++) er += sv[HH * TT + h * TT + t] * p[t];
        }

        float acc[TT];
#pragma unroll
        for (int t = 0; t < TT; t++) acc[t] = 0.f;
        float den = 0.f;

        int k = s0;
        // 2-edge software pipeline: both gathers issued before either use
        for (; k + 2 <= s1; k += 2) {
            int sA = csr_src[k], sB = csr_src[k + 1];
            const float* qa = f + (size_t)(sA * BB + b) * TT;
            const float* qb = f + (size_t)(sB * BB + b) * TT;
            float fa[TT], fb[TT];
#pragma unroll
            for (int t = 0; t < TT; t++) fa[t] = qa[t];
#pragma unroll
            for (int t = 0; t < TT; t++) fb[t] = qb[t];
            float ela = 0.f, elb = 0.f;
#pragma unroll
            for (int t = 0; t < TT; t++) {
                ela += sv[h * TT + t] * fa[t];
                elb += sv[h * TT + t] * fb[t];
            }
            float za = ela + er; za = (za >= 0.f) ? za : NEG * za;
            float zb = elb + er; zb = (zb >= 0.f) ? zb : NEG * zb;
            float wa = __expf(za), wb = __expf(zb);
            den += wa + wb;
#pragma unroll
            for (int t = 0; t < TT; t++) acc[t] += wa * fa[t] + wb * fb[t];
        }
        if (k < s1) {
            int sA = csr_src[k];
            const float* qa = f + (size_t)(sA * BB + b) * TT;
            float fa[TT];
#pragma unroll
            for (int t = 0; t < TT; t++) fa[t] = qa[t];
            float ela = 0.f;
#pragma unroll
            for (int t = 0; t < TT; t++) ela += sv[h * TT + t] * fa[t];
            float za = ela + er; za = (za >= 0.f) ? za : NEG * za;
            float wa = __expf(za);
            den += wa;
#pragma unroll
            for (int t = 0; t < TT; t++) acc[t] += wa * fa[t];
        }

        float rd = (s1 > s0) ? (1.0f / den) : 0.f;

        // W_h on aggregated feat, leaky, mean over heads via shfl_xor
        float outv[DD];
#pragma unroll
        for (int d = 0; d < DD; d++) {
            float va = 0.f;
#pragma unroll
            for (int t = 0; t < TT; t++) va += sW[(h * DD + d) * TT + t] * acc[t];
            va *= rd;
            va = (va >= 0.f) ? va : NEG * va;
            outv[d] = va * 0.25f;
        }
#pragma unroll
        for (int d = 0; d < DD; d++) {
            outv[d] += __shfl_xor(outv[d], 1, 64);
            outv[d] += __shfl_xor(outv[d], 2, 64);
        }
        if (h == 0) {
            float* gp = g + (size_t)nb * DD;
#pragma unroll
            for (int d = 0; d < DD; d++) {
                float o = outv[d];
                gp[d] = o;
                if (STATS) { lsum += o; lsq += o * o; }
            }
        }
    }
    if (STATS) {
#pragma unroll
        for (int o = 32; o > 0; o >>= 1) {
            lsum += __shfl_down(lsum, o, 64);
            lsq  += __shfl_down(lsq, o, 64);
        }
        __shared__ float ss[4][2];
        int wid = threadIdx.x >> 6, lid = threadIdx.x & 63;
        if (lid == 0) { ss[wid][0] = lsum; ss[wid][1] = lsq; }
        __syncthreads();
        if (threadIdx.x == 0) {
            float a0 = 0.f, a1 = 0.f;
#pragma unroll
            for (int w = 0; w < 4; w++) { a0 += ss[w][0]; a1 += ss[w][1]; }
            atomicAdd(&stats[0], a0);
            atomicAdd(&stats[1], a1);
        }
    }
}

// ---------------- LN(A), LN(B), average ----------------
__global__ void lncomb_kernel(const float* __restrict__ ga, const float* __restrict__ gb,
                              const float* __restrict__ stats, float* __restrict__ h) {
    int i = blockIdx.x * blockDim.x + threadIdx.x;
    if (i >= NBT) return;
    const float M = (float)NBT;
    float ma = stats[0] / M; float va = stats[1] / M - ma * ma;
    float mb = stats[2] / M; float vb = stats[3] / M - mb * mb;
    float ra = rsqrtf(va + 1e-5f), rb = rsqrtf(vb + 1e-5f);
    h[i] = 0.5f * ((ga[i] - ma) * ra + (gb[i] - mb) * rb);
}

// ---------------- final combine ----------------
__global__ void outcomb_kernel(const float* __restrict__ reg, const float* __restrict__ ga,
                               const float* __restrict__ gb, float* __restrict__ out) {
    int i = blockIdx.x * blockDim.x + threadIdx.x;
    if (i >= NBT) return;
    int nb = i / DD;
    out[i] = (reg[nb] + ga[i] + gb[i]) * (1.0f / 3.0f);
}

extern "C" void kernel_launch(void* const* d_in, const int* in_sizes, int n_in,
                              void* d_out, int out_size, void* d_ws, size_t ws_size,
                              hipStream_t stream) {
    const float* x      = (const float*)d_in[0];
    const int* ps_src   = (const int*)d_in[1];
    const int* ps_dst   = (const int*)d_in[2];
    const int* rl_src   = (const int*)d_in[3];
    const int* rl_dst   = (const int*)d_in[4];
    const float* mu_p_fc = (const float*)d_in[5];
    const float* mu_p_al = (const float*)d_in[6];
    const float* mu_p_ar = (const float*)d_in[7];
    const float* sg_p_fc = (const float*)d_in[8];
    const float* sg_p_al = (const float*)d_in[9];
    const float* sg_p_ar = (const float*)d_in[10];
    const float* mu_r_fc = (const float*)d_in[11];
    const float* mu_r_al = (const float*)d_in[12];
    const float* mu_r_ar = (const float*)d_in[13];
    const float* sg_r_fc = (const float*)d_in[14];
    const float* sg_r_al = (const float*)d_in[15];
    const float* sg_r_ar = (const float*)d_in[16];
    const float* reg_mu_w = (const float*)d_in[17];
    const float* reg_mu_b = (const float*)d_in[18];
    const float* reg_sg_w = (const float*)d_in[19];
    const float* reg_sg_b = (const float*)d_in[20];

    float* out = (float*)d_out;

    // ---- workspace carve ----
    float* fw = (float*)d_ws;
    float* mu    = fw;              fw += NBT;
    float* sigma = fw;              fw += NBT;
    float* gA    = fw;              fw += NBT;   // mu_p / mu_pf
    float* gB    = fw;              fw += NBT;   // sg_p / sg_pf
    float* gA2   = fw;              fw += NBT;   // mu_r / mu_rf
    float* gB2   = fw;              fw += NBT;   // sg_r / sg_rf
    float* hp    = fw;              fw += NBT;
    float* hrl   = fw;              fw += NBT;
    float* regmu = fw;              fw += NB;
    float* regsg = fw;              fw += NB;
    float* vbuf  = fw;              fw += 8 * 80;
    int* iw = (int*)fw;
    int* ps_off = iw;               iw += NN + 1;
    int* rl_off = iw;               iw += NN + 1;
    int* ps_csr = iw;               iw += EE;
    int* rl_csr = iw;               iw += EE;
    // zero region starts here:
    int* deg_ps = iw;               iw += NN;
    int* cur_ps = iw;               iw += NN;
    int* deg_rl = iw;               iw += NN;
    int* cur_rl = iw;               iw += NN;
    float* stats = (float*)iw;      // 8 floats
    size_t zero_bytes = (size_t)(4 * NN) * sizeof(int) + 8 * sizeof(float);
    hipMemsetAsync(deg_ps, 0, zero_bytes, stream);

    const int TPB = 256;
    const int GRID_NB  = (NB + TPB - 1) / TPB;
    const int GRID_NBH = (NBH_T + TPB - 1) / TPB;
    const int GRID_NBT = (NBT + TPB - 1) / TPB;
    const int GRID_E   = (EE + TPB - 1) / TPB;

    extract_kernel<<<GRID_NB, TPB, 0, stream>>>(x, reg_mu_w, reg_mu_b, reg_sg_w, reg_sg_b,
                                                mu, sigma, regmu, regsg);

    // CSR for both graphs
    deg_kernel<<<GRID_E, TPB, 0, stream>>>(ps_dst, deg_ps);
    deg_kernel<<<GRID_E, TPB, 0, stream>>>(rl_dst, deg_rl);
    scan_kernel<<<1, 1024, 0, stream>>>(deg_ps, ps_off);
    scan_kernel<<<1, 1024, 0, stream>>>(deg_rl, rl_off);
    fill_kernel<<<GRID_E, TPB, 0, stream>>>(ps_src, ps_dst, ps_off, cur_ps, ps_csr);
    fill_kernel<<<GRID_E, TPB, 0, stream>>>(rl_src, rl_dst, rl_off, cur_rl, rl_csr);

    // vl/vr precompute for all 8 GAT slots
    vpre_kernel<<<1, 320, 0, stream>>>(mu_p_fc, mu_p_al, mu_p_ar,
                                       sg_p_fc, sg_p_al, sg_p_ar,
                                       mu_r_fc, mu_r_al, mu_r_ar,
                                       sg_r_fc, sg_r_al, sg_r_ar, vbuf);

    // slots: 0 mu_p L0, 1 sg_p L0, 2 mu_r L0, 3 sg_r L0, 4 mu_p L1, 5 sg_p L1, 6 mu_r L1, 7 sg_r L1
    // ---- layer 0: four single-GATs ----
    gat1_kernel<true><<<GRID_NBH, TPB, 0, stream>>>(
        mu, mu_p_fc, vbuf + 0 * 80, ps_off, ps_csr, gA, stats + 0);
    gat1_kernel<true><<<GRID_NBH, TPB, 0, stream>>>(
        sigma, sg_p_fc, vbuf + 1 * 80, ps_off, ps_csr, gB, stats + 2);
    gat1_kernel<true><<<GRID_NBH, TPB, 0, stream>>>(
        mu, mu_r_fc, vbuf + 2 * 80, rl_off, rl_csr, gA2, stats + 4);
    gat1_kernel<true><<<GRID_NBH, TPB, 0, stream>>>(
        sigma, sg_r_fc, vbuf + 3 * 80, rl_off, rl_csr, gB2, stats + 6);
    lncomb_kernel<<<GRID_NBT, TPB, 0, stream>>>(gA, gB, stats + 0, hp);
    lncomb_kernel<<<GRID_NBT, TPB, 0, stream>>>(gA2, gB2, stats + 4, hrl);

    // ---- final layers: four single-GATs ----
    gat1_kernel<false><<<GRID_NBH, TPB, 0, stream>>>(
        hp, mu_p_fc + 400, vbuf + 4 * 80, ps_off, ps_csr, gA, nullptr);
    gat1_kernel<false><<<GRID_NBH, TPB, 0, stream>>>(
        hp, sg_p_fc + 400, vbuf + 5 * 80, ps_off, ps_csr, gB, nullptr);
    gat1_kernel<false><<<GRID_NBH, TPB, 0, stream>>>(
        hrl, mu_r_fc + 400, vbuf + 6 * 80, rl_off, rl_csr, gA2, nullptr);
    gat1_kernel<false><<<GRID_NBH, TPB, 0, stream>>>(
        hrl, sg_r_fc + 400, vbuf + 7 * 80, rl_off, rl_csr, gB2, nullptr);

    outcomb_kernel<<<GRID_NBT, TPB, 0, stream>>>(regmu, gA, gA2, out);
    outcomb_kernel<<<GRID_NBT, TPB, 0, stream>>>(regsg, gB, gB2, out + NBT);
}

// Round 7
// 834.524 us; speedup vs baseline: 1.0395x; 1.0395x over previous
//
#include <hip/hip_runtime.h>

#define NN 10000
#define BB 32
#define EE 40000
#define HH 4
#define DD 10
#define TT 10
#define FS 12          // padded feat row stride (48 B, 16-B aligned)
#define NEG 0.2f

#define NB   (NN*BB)          // 320000
#define NBH_T (NB*HH)         // 1280000 threads for gat kernels
#define NBT  (NN*BB*TT)       // 3200000
#define NBF  (NN*BB*FS)       // 3840000 padded feat elems

// ---------------- extract mu/sigma + regression heads ----------------
__global__ void extract_kernel(const float* __restrict__ x,
                               const float* __restrict__ wmu, const float* __restrict__ bmu,
                               const float* __restrict__ wsg, const float* __restrict__ bsg,
                               float* __restrict__ mu, float* __restrict__ sg,
                               float* __restrict__ regmu, float* __restrict__ regsg) {
    int i = blockIdx.x * blockDim.x + threadIdx.x;   // over N*B
    if (i >= NB) return;
    int n = i / BB, b = i % BB;
    float smu = 0.f, ssg = 0.f;
    float muv[TT], sgv[TT];
#pragma unroll
    for (int t = 0; t < TT; t++) {
        size_t xi = (((size_t)t * NN + n) * BB + b) * 3;
        float m = x[xi], s = x[xi + 1];
        muv[t] = m; sgv[t] = s;
        smu += m * wmu[t];
        ssg += s * wsg[t];
    }
#pragma unroll
    for (int t = 0; t < TT; t++) {
        mu[(size_t)i * FS + t] = muv[t];
        sg[(size_t)i * FS + t] = sgv[t];
    }
    regmu[i] = smu + bmu[0];
    regsg[i] = ssg + bsg[0];
}

// ---------------- CSR build ----------------
__global__ void deg_kernel(const int* __restrict__ dst, int* __restrict__ deg) {
    int e = blockIdx.x * blockDim.x + threadIdx.x;
    if (e < EE) atomicAdd(&deg[dst[e]], 1);
}

__global__ void scan_kernel(const int* __restrict__ deg, int* __restrict__ off) {
    __shared__ int sm[1024];
    __shared__ int carry_s;
    if (threadIdx.x == 0) { carry_s = 0; off[0] = 0; }
    __syncthreads();
    for (int base = 0; base < NN; base += 1024) {
        int i = base + (int)threadIdx.x;
        int v = (i < NN) ? deg[i] : 0;
        sm[threadIdx.x] = v;
        __syncthreads();
        for (int s = 1; s < 1024; s <<= 1) {
            int t = (threadIdx.x >= (unsigned)s) ? sm[threadIdx.x - s] : 0;
            __syncthreads();
            sm[threadIdx.x] += t;
            __syncthreads();
        }
        if (i < NN) off[i + 1] = carry_s + sm[threadIdx.x];
        __syncthreads();
        if (threadIdx.x == 0) carry_s += sm[1023];
        __syncthreads();
    }
}

__global__ void fill_kernel(const int* __restrict__ src, const int* __restrict__ dst,
                            const int* __restrict__ off, int* __restrict__ cursor,
                            int* __restrict__ csr_src) {
    int e = blockIdx.x * blockDim.x + threadIdx.x;
    if (e < EE) {
        int d = dst[e];
        int p = atomicAdd(&cursor[d], 1);
        csr_src[off[d] + p] = src[e];
    }
}

// ---------------- precompute vl/vr for all 8 GATs ----------------
// vbuf layout: 8 slots of [vl(H*T=40) | vr(40)];
__global__ void vpre_kernel(const float* __restrict__ fc0, const float* __restrict__ al0, const float* __restrict__ ar0,
                            const float* __restrict__ fc1, const float* __restrict__ al1, const float* __restrict__ ar1,
                            const float* __restrict__ fc2, const float* __restrict__ al2, const float* __restrict__ ar2,
                            const float* __restrict__ fc3, const float* __restrict__ al3, const float* __restrict__ ar3,
                            float* __restrict__ vbuf) {
    int j = threadIdx.x;                 // 0..319
    if (j >= 320) return;
    int g = j / 40, r = j % 40;
    int h = r / 10, t = r % 10;
    int which = g & 3, layer = g >> 2;
    const float* fc; const float* al; const float* ar;
    if (which == 0)      { fc = fc0; al = al0; ar = ar0; }
    else if (which == 1) { fc = fc1; al = al1; ar = ar1; }
    else if (which == 2) { fc = fc2; al = al2; ar = ar2; }
    else                 { fc = fc3; al = al3; ar = ar3; }
    fc += layer * (HH * DD * TT);
    al += layer * (HH * DD);
    ar += layer * (HH * DD);
    float vl = 0.f, vr = 0.f;
#pragma unroll
    for (int d = 0; d < DD; d++) {
        float w = fc[(h * DD + d) * TT + t];
        vl += al[h * DD + d] * w;
        vr += ar[h * DD + d] * w;
    }
    vbuf[g * 80 + r] = vl;
    vbuf[g * 80 + 40 + r] = vr;
}

// ---------------- quad-GAT: 4 independent GAT configs in one dispatch -------
// blockIdx.y selects config. Thread per (node, batch, head).
// r6 post-mortem: spill gone (VGPR 48) but per-unit time unchanged ->
// latency-bound gather, not registers. This round: (a) vl hoisted to regs
// (no LDS reads in edge loop), (b) feat rows padded to 48 B and loaded as
// float4+float4+float2 (3 VMEM ops/edge instead of 10), (c) 4 configs per
// dispatch for 4x resident waves.
struct GatCfg {
    const float* f; const float* W; const float* v;
    const int* off; const int* csr;
    float* g; float* stats;
};
struct GatCfg4 { GatCfg c[4]; };

#define LOAD_ROW(dst, q)                                        \
    {                                                           \
        float4 _r0 = *(const float4*)(q);                       \
        float4 _r1 = *(const float4*)((q) + 4);                 \
        float2 _r2 = *(const float2*)((q) + 8);                 \
        dst[0]=_r0.x; dst[1]=_r0.y; dst[2]=_r0.z; dst[3]=_r0.w; \
        dst[4]=_r1.x; dst[5]=_r1.y; dst[6]=_r1.z; dst[7]=_r1.w; \
        dst[8]=_r2.x; dst[9]=_r2.y;                             \
    }

template <bool STATS>
__global__ void __launch_bounds__(256)
gat4_kernel(GatCfg4 cfgs) {
    const GatCfg cfg = cfgs.c[blockIdx.y];
    __shared__ float sW[HH * DD * TT];      // 400
    __shared__ float sv[2 * HH * TT];       // 80: [vl(40) | vr(40)]
    for (int k = threadIdx.x; k < HH * DD * TT; k += blockDim.x) sW[k] = cfg.W[k];
    if (threadIdx.x < 2 * HH * TT) sv[threadIdx.x] = cfg.v[threadIdx.x];
    __syncthreads();

    const float* __restrict__ f = cfg.f;
    const int* __restrict__ csr = cfg.csr;

    int i = blockIdx.x * blockDim.x + threadIdx.x;   // over NB*HH
    float lsum = 0.f, lsq = 0.f;
    if (i < NBH_T) {
        int h  = i & 3;
        int nb = i >> 2;          // n*32 + b
        int b  = nb & 31;
        int n  = nb >> 5;
        int s0 = cfg.off[n], s1 = cfg.off[n + 1];

        // attention vector for this head in registers (out of the hot loop)
        float vl[TT];
#pragma unroll
        for (int t = 0; t < TT; t++) vl[t] = sv[h * TT + t];

        // er from self features
        float er = 0.f;
        {
            const float* p = f + (size_t)nb * FS;
            float fs[TT];
            LOAD_ROW(fs, p);
#pragma unroll
            for (int t = 0; t < TT; t++) er += sv[HH * TT + h * TT + t] * fs[t];
        }

        float acc[TT];
#pragma unroll
        for (int t = 0; t < TT; t++) acc[t] = 0.f;
        float den = 0.f;

        int k = s0;
        for (; k + 2 <= s1; k += 2) {
            int sA = csr[k], sB = csr[k + 1];
            const float* qa = f + (size_t)(sA * BB + b) * FS;
            const float* qb = f + (size_t)(sB * BB + b) * FS;
            float fa[TT], fb[TT];
            LOAD_ROW(fa, qa);
            LOAD_ROW(fb, qb);
            float ela = 0.f, elb = 0.f;
#pragma unroll
            for (int t = 0; t < TT; t++) {
                ela += vl[t] * fa[t];
                elb += vl[t] * fb[t];
            }
            float za = ela + er; za = (za >= 0.f) ? za : NEG * za;
            float zb = elb + er; zb = (zb >= 0.f) ? zb : NEG * zb;
            float wa = __expf(za), wb = __expf(zb);
            den += wa + wb;
#pragma unroll
            for (int t = 0; t < TT; t++) acc[t] += wa * fa[t] + wb * fb[t];
        }
        if (k < s1) {
            int sA = csr[k];
            const float* qa = f + (size_t)(sA * BB + b) * FS;
            float fa[TT];
            LOAD_ROW(fa, qa);
            float ela = 0.f;
#pragma unroll
            for (int t = 0; t < TT; t++) ela += vl[t] * fa[t];
            float za = ela + er; za = (za >= 0.f) ? za : NEG * za;
            float wa = __expf(za);
            den += wa;
#pragma unroll
            for (int t = 0; t < TT; t++) acc[t] += wa * fa[t];
        }

        float rd = (s1 > s0) ? (1.0f / den) : 0.f;

        // W_h on aggregated feat, leaky, mean over heads via shfl_xor
        float outv[DD];
#pragma unroll
        for (int d = 0; d < DD; d++) {
            float va = 0.f;
#pragma unroll
            for (int t = 0; t < TT; t++) va += sW[(h * DD + d) * TT + t] * acc[t];
            va *= rd;
            va = (va >= 0.f) ? va : NEG * va;
            outv[d] = va * 0.25f;
        }
#pragma unroll
        for (int d = 0; d < DD; d++) {
            outv[d] += __shfl_xor(outv[d], 1, 64);
            outv[d] += __shfl_xor(outv[d], 2, 64);
        }
        if (h == 0) {
            float* gp = cfg.g + (size_t)nb * DD;
#pragma unroll
            for (int d = 0; d < DD; d++) {
                float o = outv[d];
                gp[d] = o;
                if (STATS) { lsum += o; lsq += o * o; }
            }
        }
    }
    if (STATS) {
#pragma unroll
        for (int o = 32; o > 0; o >>= 1) {
            lsum += __shfl_down(lsum, o, 64);
            lsq  += __shfl_down(lsq, o, 64);
        }
        __shared__ float ss[4][2];
        int wid = threadIdx.x >> 6, lid = threadIdx.x & 63;
        if (lid == 0) { ss[wid][0] = lsum; ss[wid][1] = lsq; }
        __syncthreads();
        if (threadIdx.x == 0) {
            float a0 = 0.f, a1 = 0.f;
#pragma unroll
            for (int w = 0; w < 4; w++) { a0 += ss[w][0]; a1 += ss[w][1]; }
            atomicAdd(&cfg.stats[0], a0);
            atomicAdd(&cfg.stats[1], a1);
        }
    }
}

// ---------------- LN(A), LN(B), average; writes padded feat rows ----------
__global__ void lncomb_kernel(const float* __restrict__ ga, const float* __restrict__ gb,
                              const float* __restrict__ stats, float* __restrict__ h) {
    int i = blockIdx.x * blockDim.x + threadIdx.x;
    if (i >= NBT) return;
    const float M = (float)NBT;
    float ma = stats[0] / M; float va = stats[1] / M - ma * ma;
    float mb = stats[2] / M; float vb = stats[3] / M - mb * mb;
    float ra = rsqrtf(va + 1e-5f), rb = rsqrtf(vb + 1e-5f);
    int nb = i / DD, t = i - nb * DD;
    h[(size_t)nb * FS + t] = 0.5f * ((ga[i] - ma) * ra + (gb[i] - mb) * rb);
}

// ---------------- final combine ----------------
__global__ void outcomb_kernel(const float* __restrict__ reg, const float* __restrict__ ga,
                               const float* __restrict__ gb, float* __restrict__ out) {
    int i = blockIdx.x * blockDim.x + threadIdx.x;
    if (i >= NBT) return;
    int nb = i / DD;
    out[i] = (reg[nb] + ga[i] + gb[i]) * (1.0f / 3.0f);
}

extern "C" void kernel_launch(void* const* d_in, const int* in_sizes, int n_in,
                              void* d_out, int out_size, void* d_ws, size_t ws_size,
                              hipStream_t stream) {
    const float* x      = (const float*)d_in[0];
    const int* ps_src   = (const int*)d_in[1];
    const int* ps_dst   = (const int*)d_in[2];
    const int* rl_src   = (const int*)d_in[3];
    const int* rl_dst   = (const int*)d_in[4];
    const float* mu_p_fc = (const float*)d_in[5];
    const float* mu_p_al = (const float*)d_in[6];
    const float* mu_p_ar = (const float*)d_in[7];
    const float* sg_p_fc = (const float*)d_in[8];
    const float* sg_p_al = (const float*)d_in[9];
    const float* sg_p_ar = (const float*)d_in[10];
    const float* mu_r_fc = (const float*)d_in[11];
    const float* mu_r_al = (const float*)d_in[12];
    const float* mu_r_ar = (const float*)d_in[13];
    const float* sg_r_fc = (const float*)d_in[14];
    const float* sg_r_al = (const float*)d_in[15];
    const float* sg_r_ar = (const float*)d_in[16];
    const float* reg_mu_w = (const float*)d_in[17];
    const float* reg_mu_b = (const float*)d_in[18];
    const float* reg_sg_w = (const float*)d_in[19];
    const float* reg_sg_b = (const float*)d_in[20];

    float* out = (float*)d_out;

    // ---- workspace carve ----
    float* fw = (float*)d_ws;
    float* mu    = fw;              fw += NBF;   // padded stride-12 feats
    float* sigma = fw;              fw += NBF;
    float* hp    = fw;              fw += NBF;
    float* hrl   = fw;              fw += NBF;
    float* gA    = fw;              fw += NBT;   // stride-10 GAT outputs
    float* gB    = fw;              fw += NBT;
    float* gA2   = fw;              fw += NBT;
    float* gB2   = fw;              fw += NBT;
    float* regmu = fw;              fw += NB;
    float* regsg = fw;              fw += NB;
    float* vbuf  = fw;              fw += 8 * 80;
    int* iw = (int*)fw;
    int* ps_off = iw;               iw += NN + 1;
    int* rl_off = iw;               iw += NN + 1;
    int* ps_csr = iw;               iw += EE;
    int* rl_csr = iw;               iw += EE;
    // zero region starts here:
    int* deg_ps = iw;               iw += NN;
    int* cur_ps = iw;               iw += NN;
    int* deg_rl = iw;               iw += NN;
    int* cur_rl = iw;               iw += NN;
    float* stats = (float*)iw;      // 8 floats
    size_t zero_bytes = (size_t)(4 * NN) * sizeof(int) + 8 * sizeof(float);
    hipMemsetAsync(deg_ps, 0, zero_bytes, stream);

    const int TPB = 256;
    const int GRID_NB  = (NB + TPB - 1) / TPB;
    const int GRID_NBH = (NBH_T + TPB - 1) / TPB;   // 5000
    const int GRID_NBT = (NBT + TPB - 1) / TPB;
    const int GRID_E   = (EE + TPB - 1) / TPB;

    extract_kernel<<<GRID_NB, TPB, 0, stream>>>(x, reg_mu_w, reg_mu_b, reg_sg_w, reg_sg_b,
                                                mu, sigma, regmu, regsg);

    // CSR for both graphs
    deg_kernel<<<GRID_E, TPB, 0, stream>>>(ps_dst, deg_ps);
    deg_kernel<<<GRID_E, TPB, 0, stream>>>(rl_dst, deg_rl);
    scan_kernel<<<1, 1024, 0, stream>>>(deg_ps, ps_off);
    scan_kernel<<<1, 1024, 0, stream>>>(deg_rl, rl_off);
    fill_kernel<<<GRID_E, TPB, 0, stream>>>(ps_src, ps_dst, ps_off, cur_ps, ps_csr);
    fill_kernel<<<GRID_E, TPB, 0, stream>>>(rl_src, rl_dst, rl_off, cur_rl, rl_csr);

    // vl/vr precompute for all 8 GAT slots
    vpre_kernel<<<1, 320, 0, stream>>>(mu_p_fc, mu_p_al, mu_p_ar,
                                       sg_p_fc, sg_p_al, sg_p_ar,
                                       mu_r_fc, mu_r_al, mu_r_ar,
                                       sg_r_fc, sg_r_al, sg_r_ar, vbuf);

    // slots: 0 mu_p L0, 1 sg_p L0, 2 mu_r L0, 3 sg_r L0, 4 mu_p L1, 5 sg_p L1, 6 mu_r L1, 7 sg_r L1
    // ---- layer 0: 4 GATs in one dispatch ----
    {
        GatCfg4 c;
        c.c[0] = { mu,    mu_p_fc,       vbuf + 0 * 80, ps_off, ps_csr, gA,  stats + 0 };
        c.c[1] = { sigma, sg_p_fc,       vbuf + 1 * 80, ps_off, ps_csr, gB,  stats + 2 };
        c.c[2] = { mu,    mu_r_fc,       vbuf + 2 * 80, rl_off, rl_csr, gA2, stats + 4 };
        c.c[3] = { sigma, sg_r_fc,       vbuf + 3 * 80, rl_off, rl_csr, gB2, stats + 6 };
        dim3 grid(GRID_NBH, 4, 1);
        gat4_kernel<true><<<grid, TPB, 0, stream>>>(c);
    }
    lncomb_kernel<<<GRID_NBT, TPB, 0, stream>>>(gA, gB, stats + 0, hp);
    lncomb_kernel<<<GRID_NBT, TPB, 0, stream>>>(gA2, gB2, stats + 4, hrl);

    // ---- final layers: 4 GATs in one dispatch ----
    {
        GatCfg4 c;
        c.c[0] = { hp,  mu_p_fc + 400, vbuf + 4 * 80, ps_off, ps_csr, gA,  nullptr };
        c.c[1] = { hp,  sg_p_fc + 400, vbuf + 5 * 80, ps_off, ps_csr, gB,  nullptr };
        c.c[2] = { hrl, mu_r_fc + 400, vbuf + 6 * 80, rl_off, rl_csr, gA2, nullptr };
        c.c[3] = { hrl, sg_r_fc + 400, vbuf + 7 * 80, rl_off, rl_csr, gB2, nullptr };
        dim3 grid(GRID_NBH, 4, 1);
        gat4_kernel<false><<<grid, TPB, 0, stream>>>(c);
    }

    outcomb_kernel<<<GRID_NBT, TPB, 0, stream>>>(regmu, gA, gA2, out);
    outcomb_kernel<<<GRID_NBT, TPB, 0, stream>>>(regsg, gB, gB2, out + NBT);
}